// Round 2
// baseline (377.487 us; speedup 1.0000x reference)
//
#include <hip/hip_runtime.h>

#define HDIM 1024
#define H4   4096
#define NH2  512
#define VD   32000
#define WINN 129
#define NEGV (-1e30f)

// ws float offsets
#define X_    0        // 1024: layer input x / h_t / later fc1 output vector
#define HP_   1024     // 2048: h0 as f32 (2 layers)
#define CP_   3072     // 2048: c0 as f32
#define G_    5120     // 4096: lstm gates
#define ATT1_ 9216     // 512
#define CAT_  9728     // 2048: [ctx | h_t]
#define A_    11776    // 132: scores then attention weights
#define SC_   11908    // scalars: p, max_logit, logsumexp
#define IW_   11912    // int slots: ws_i, we_i
#define LOG_  12288    // 32000 logits

// d_out float element offsets
#define O_Y   0
#define O_OUT 32000
#define O_HN  33024
#define O_CN  35072
#define O_A   37120

// dot of 16 f32 (w, vectorized) with 16 f32 (x)
__device__ __forceinline__ float dot16f(const float* __restrict__ w, const float* __restrict__ x){
  float4 a0 = *(const float4*)w;
  float4 a1 = *(const float4*)(w+4);
  float4 a2 = *(const float4*)(w+8);
  float4 a3 = *(const float4*)(w+12);
  float acc = 0.f;
  acc += a0.x*x[0] + a0.y*x[1] + a0.z*x[2] + a0.w*x[3];
  acc += a1.x*x[4] + a1.y*x[5] + a1.z*x[6] + a1.w*x[7];
  acc += a2.x*x[8] + a2.y*x[9] + a2.z*x[10] + a2.w*x[11];
  acc += a3.x*x[12] + a3.y*x[13] + a3.z*x[14] + a3.w*x[15];
  return acc;
}
__device__ __forceinline__ float wred(float v){
  #pragma unroll
  for(int off=32; off; off>>=1) v += __shfl_xor(v, off, 64);
  return v;
}
__device__ __forceinline__ float wmax(float v){
  #pragma unroll
  for(int off=32; off; off>>=1) v = fmaxf(v, __shfl_xor(v, off, 64));
  return v;
}
__device__ __forceinline__ float sigf(float x){ return 1.f/(1.f+expf(-x)); }

// ---- kernels ----

__global__ __launch_bounds__(256) void k_embed(const int* __restrict__ word,
    const float* __restrict__ emb, const float* __restrict__ h0, const float* __restrict__ c0,
    float* __restrict__ ws){
  int i = blockIdx.x*256 + threadIdx.x;   // 0..5119
  if (i < 1024)      ws[X_  + i]        = emb[(size_t)word[0]*HDIM + i];
  else if (i < 3072) ws[HP_ + (i-1024)] = h0[i-1024];
  else               ws[CP_ + (i-3072)] = c0[i-3072];
}

__global__ __launch_bounds__(256) void k_lstm_gemv(
    const float* __restrict__ wih, const float* __restrict__ whh,
    const float* __restrict__ bih, const float* __restrict__ bhh,
    float* __restrict__ ws, int l){
  int gid = blockIdx.x*256 + threadIdx.x;
  int r = gid >> 6, lane = gid & 63;      // r in 0..4095
  const float* wi = wih + ((size_t)r<<10) + lane*16;
  const float* wh = whh + ((size_t)r<<10) + lane*16;
  float acc = dot16f(wi, ws + X_ + lane*16)
            + dot16f(wh, ws + HP_ + l*HDIM + lane*16);
  acc = wred(acc);
  if (lane==0) ws[G_ + r] = acc + bih[r] + bhh[r];
}

__global__ __launch_bounds__(256) void k_lstm_act(float* __restrict__ ws,
    float* __restrict__ hn, float* __restrict__ cn, int l){
  int j = blockIdx.x*256 + threadIdx.x;   // 0..1023
  float gi = ws[G_ + j], gf = ws[G_ + 1024 + j], gg = ws[G_ + 2048 + j], go = ws[G_ + 3072 + j];
  float cp = ws[CP_ + l*HDIM + j];
  float c  = sigf(gf)*cp + sigf(gi)*tanhf(gg);
  float h  = sigf(go)*tanhf(c);
  ws[X_ + j] = h;
  if (l==1) ws[CAT_ + HDIM + j] = h;
  hn[l*HDIM + j] = h;
  cn[l*HDIM + j] = c;
}

__global__ __launch_bounds__(256) void k_att1(const float* __restrict__ w,
    const float* __restrict__ b, float* __restrict__ ws){
  int gid = blockIdx.x*256 + threadIdx.x;
  int r = gid >> 6, lane = gid & 63;      // r in 0..511
  float acc = dot16f(w + ((size_t)r<<10) + lane*16, ws + X_ + lane*16);
  acc = wred(acc);
  if (lane==0) ws[ATT1_ + r] = tanhf(acc + b[r]);
}

__global__ void k_att2(const float* __restrict__ w, const float* __restrict__ b,
    const int* __restrict__ slen, float* __restrict__ ws){
  int lane = threadIdx.x & 63;
  float4 u0 = *(const float4*)(w + lane*8);
  float4 u1 = *(const float4*)(w + lane*8 + 4);
  const float* x = ws + ATT1_ + lane*8;
  float acc = u0.x*x[0] + u0.y*x[1] + u0.z*x[2] + u0.w*x[3]
            + u1.x*x[4] + u1.y*x[5] + u1.z*x[6] + u1.w*x[7];
  acc = wred(acc);
  if (lane==0){
    float val = acc + b[0];
    float Sf  = (float)slen[0];
    float p   = Sf * sigf(val);
    ws[SC_] = p;
    int wsi = (int)rintf(fmaxf(p - 64.f, 0.f));
    int wei = (int)rintf(fminf(p + 64.f, Sf - 1.f));
    ((int*)ws)[IW_]   = wsi;
    ((int*)ws)[IW_+1] = wei;
  }
}

__global__ __launch_bounds__(256) void k_scores(const float* __restrict__ enc,
    const int* __restrict__ slen, float* __restrict__ ws){
  int gid = blockIdx.x*256 + threadIdx.x;
  int k = gid >> 6, lane = gid & 63;
  if (k >= WINN) return;
  int wsi = ((int*)ws)[IW_], wei = ((int*)ws)[IW_+1];
  int idx = wsi + k;
  int smax = slen[0]-1;
  int ci = idx > smax ? smax : (idx < 0 ? 0 : idx);
  float d = dot16f(enc + ((size_t)ci<<10) + lane*16, ws + X_ + lane*16);
  d = wred(d);
  if (lane==0) ws[A_ + k] = (idx <= wei) ? d : NEGV;
}

__global__ void k_softmax(float* __restrict__ ws, float* __restrict__ aout){
  __shared__ float red[8];
  int t = threadIdx.x;                    // 256 threads
  float p = ws[SC_];
  int wsi = ((int*)ws)[IW_], wei = ((int*)ws)[IW_+1];
  float s = (t < WINN) ? ws[A_ + t] : -INFINITY;
  float m = wmax(s);
  if ((t&63)==0) red[t>>6] = m;
  __syncthreads();
  m = fmaxf(fmaxf(red[0],red[1]), fmaxf(red[2],red[3]));
  float e = (t < WINN) ? expf(s - m) : 0.f;
  float sm = wred(e);
  if ((t&63)==0) red[4 + (t>>6)] = sm;
  __syncthreads();
  sm = red[4]+red[5]+red[6]+red[7];
  if (t < WINN){
    int idx = wsi + t;
    float a = e / sm;
    a = (idx <= wei) ? a * expf(((float)idx - p) * (1.f/2048.f)) : 0.f;
    ws[A_ + t] = a;
    aout[t] = a;
  }
}

__global__ __launch_bounds__(256) void k_ctx(const float* __restrict__ enc,
    const int* __restrict__ slen, float* __restrict__ ws){
  __shared__ float av[WINN];
  __shared__ int   ci[WINN];
  int t = threadIdx.x;
  if (t < WINN){
    av[t] = ws[A_ + t];
    int idx = ((int*)ws)[IW_] + t;
    int smax = slen[0]-1;
    ci[t] = idx > smax ? smax : (idx < 0 ? 0 : idx);
  }
  __syncthreads();
  int i = blockIdx.x*256 + t;             // 0..1023
  float acc = 0.f;
  for (int k=0; k<WINN; k++) acc += av[k] * enc[((size_t)ci[k]<<10) + i];
  ws[CAT_ + i] = acc;
}

__global__ __launch_bounds__(256) void k_fc1(const float* __restrict__ w,
    const float* __restrict__ b, float* __restrict__ ws, float* __restrict__ oout){
  int gid = blockIdx.x*256 + threadIdx.x;
  int r = gid >> 6, lane = gid & 63;      // r in 0..1023
  const float* wr = w + ((size_t)r<<11) + lane*32;
  float acc = dot16f(wr, ws + CAT_ + lane*32) + dot16f(wr+16, ws + CAT_ + lane*32 + 16);
  acc = wred(acc);
  if (lane==0){
    float o = tanhf(acc + b[r]);
    ws[X_ + r] = o;
    oout[r] = o;
  }
}

__global__ __launch_bounds__(256) void k_fc2(const float* __restrict__ w,
    const float* __restrict__ b, float* __restrict__ ws){
  int gid = blockIdx.x*256 + threadIdx.x;
  int r = gid >> 6, lane = gid & 63;      // r in 0..31999
  float acc = dot16f(w + ((size_t)r<<10) + lane*16, ws + X_ + lane*16);
  acc = wred(acc);
  if (lane==0) ws[LOG_ + r] = acc + b[r];
}

__global__ __launch_bounds__(1024) void k_lse(float* __restrict__ ws){
  __shared__ float red[16];
  int t = threadIdx.x;                    // 1024 threads
  float m = -INFINITY;
  for (int v=t; v<VD; v+=1024) m = fmaxf(m, ws[LOG_ + v]);
  m = wmax(m);
  if ((t&63)==0) red[t>>6] = m;
  __syncthreads();
  if (t==0){ float mm=red[0]; for(int i=1;i<16;i++) mm=fmaxf(mm,red[i]); red[0]=mm; }
  __syncthreads();
  float M = red[0];
  __syncthreads();
  float s = 0.f;
  for (int v=t; v<VD; v+=1024) s += expf(ws[LOG_ + v] - M);
  s = wred(s);
  if ((t&63)==0) red[t>>6] = s;
  __syncthreads();
  if (t==0){
    float ss=0.f; for(int i=0;i<16;i++) ss+=red[i];
    ws[SC_+1] = M; ws[SC_+2] = logf(ss);
  }
}

__global__ __launch_bounds__(256) void k_y(const float* __restrict__ ws, float* __restrict__ y){
  int v = blockIdx.x*256 + threadIdx.x;
  if (v < VD) y[v] = ws[LOG_ + v] - ws[SC_+1] - ws[SC_+2];
}

extern "C" void kernel_launch(void* const* d_in, const int* in_sizes, int n_in,
                              void* d_out, int out_size, void* d_ws, size_t ws_size,
                              hipStream_t stream) {
  const int*   slen = (const int*)d_in[0];
  const float* enc  = (const float*)d_in[1];
  const int*   word = (const int*)d_in[2];
  const float* h0   = (const float*)d_in[3];
  const float* c0   = (const float*)d_in[4];
  const float* emb  = (const float*)d_in[5];
  const float* wih  = (const float*)d_in[6];
  const float* whh  = (const float*)d_in[7];
  const float* bih  = (const float*)d_in[8];
  const float* bhh  = (const float*)d_in[9];
  const float* a1w  = (const float*)d_in[10];
  const float* a1b  = (const float*)d_in[11];
  const float* a2w  = (const float*)d_in[12];
  const float* a2b  = (const float*)d_in[13];
  const float* f1w  = (const float*)d_in[14];
  const float* f1b  = (const float*)d_in[15];
  const float* f2w  = (const float*)d_in[16];
  const float* f2b  = (const float*)d_in[17];
  float* ws  = (float*)d_ws;
  float* out = (float*)d_out;

  k_embed<<<20,256,0,stream>>>(word, emb, h0, c0, ws);
  for (int l=0; l<2; l++){
    k_lstm_gemv<<<1024,256,0,stream>>>(wih + (size_t)l*H4*HDIM, whh + (size_t)l*H4*HDIM,
                                       bih + l*H4, bhh + l*H4, ws, l);
    k_lstm_act<<<4,256,0,stream>>>(ws, out + O_HN, out + O_CN, l);
  }
  k_att1<<<128,256,0,stream>>>(a1w, a1b, ws);
  k_att2<<<1,64,0,stream>>>(a2w, a2b, slen, ws);
  k_scores<<<33,256,0,stream>>>(enc, slen, ws);
  k_softmax<<<1,256,0,stream>>>(ws, out + O_A);
  k_ctx<<<4,256,0,stream>>>(enc, slen, ws);
  k_fc1<<<256,256,0,stream>>>(f1w, f1b, ws, out + O_OUT);
  k_fc2<<<8000,256,0,stream>>>(f2w, f2b, ws);
  k_lse<<<1,1024,0,stream>>>(ws);
  k_y<<<125,256,0,stream>>>(ws, out + O_Y);
}

// Round 3
// 361.852 us; speedup vs baseline: 1.0432x; 1.0432x over previous
//
#include <hip/hip_runtime.h>

#define HDIM 1024
#define H4   4096
#define VD   32000
#define WINN 129
#define NEGV (-1e30f)

// ws float offsets
#define X_    0        // 1024: h of current layer / fc1 output vector
#define G_    5120     // 4096: lstm gates
#define ATT1_ 9216     // 512
#define CAT_  9728     // 2048: [ctx | h_t]
#define A_    11776    // 129: scores then attention weights
#define SC_   11908    // p
#define IW_   11912    // int slots: ws_i, we_i
#define PART_ 12000    // 32 partial max + 32 partial sumexp
#define LOG_  12288    // 32000 logits

// d_out float element offsets
#define O_Y   0
#define O_OUT 32000
#define O_HN  33024
#define O_CN  35072
#define O_A   37120

__device__ __forceinline__ float wred(float v){
  #pragma unroll
  for(int off=32; off; off>>=1) v += __shfl_xor(v, off, 64);
  return v;
}
__device__ __forceinline__ float wmax(float v){
  #pragma unroll
  for(int off=32; off; off>>=1) v = fmaxf(v, __shfl_xor(v, off, 64));
  return v;
}
__device__ __forceinline__ float sigf(float x){ return 1.f/(1.f+expf(-x)); }
__device__ __forceinline__ float dot4(float4 a, float4 b){
  return a.x*b.x + a.y*b.y + a.z*b.z + a.w*b.w;
}

// ---- kernels ----

// one wave per row; contiguous 1KB per load instruction
__global__ __launch_bounds__(256) void k_lstm_gemv(
    const float* __restrict__ wih, const float* __restrict__ whh,
    const float* __restrict__ bih, const float* __restrict__ bhh,
    const float* __restrict__ xin, const int* __restrict__ word,
    const float* __restrict__ emb, const float* __restrict__ hin,
    float* __restrict__ gout){
  int gid = blockIdx.x*256 + threadIdx.x;
  int r = gid >> 6, lane = gid & 63;      // r in 0..4095
  const float* xp = word ? (emb + ((size_t)word[0]<<10)) : xin;
  const float* wi = wih + ((size_t)r<<10);
  const float* wh = whh + ((size_t)r<<10);
  float acc = 0.f;
  #pragma unroll
  for (int j=0; j<4; j++){
    int o = lane*4 + 256*j;
    acc += dot4(*(const float4*)(wi+o), *(const float4*)(xp+o));
    acc += dot4(*(const float4*)(wh+o), *(const float4*)(hin+o));
  }
  acc = wred(acc);
  if (lane==0) gout[r] = acc + bih[r] + bhh[r];
}

__global__ __launch_bounds__(256) void k_lstm_act(
    const float* __restrict__ g, const float* __restrict__ c0l,
    float* __restrict__ ws, float* __restrict__ hn, float* __restrict__ cn, int last){
  int j = blockIdx.x*256 + threadIdx.x;   // 0..1023
  float gi = g[j], gf = g[1024+j], gg = g[2048+j], go = g[3072+j];
  float c  = sigf(gf)*c0l[j] + sigf(gi)*tanhf(gg);
  float h  = sigf(go)*tanhf(c);
  ws[X_ + j] = h;
  if (last) ws[CAT_ + HDIM + j] = h;
  hn[j] = h;
  cn[j] = c;
}

__global__ __launch_bounds__(256) void k_att1(const float* __restrict__ w,
    const float* __restrict__ b, float* __restrict__ ws){
  int gid = blockIdx.x*256 + threadIdx.x;
  int r = gid >> 6, lane = gid & 63;      // r in 0..511
  const float* wr = w + ((size_t)r<<10);
  float acc = 0.f;
  #pragma unroll
  for (int j=0; j<4; j++){
    int o = lane*4 + 256*j;
    acc += dot4(*(const float4*)(wr+o), *(const float4*)(ws+X_+o));
  }
  acc = wred(acc);
  if (lane==0) ws[ATT1_ + r] = tanhf(acc + b[r]);
}

// att2 computed redundantly per wave (removes a serial launch), then 129 score rows
__global__ __launch_bounds__(256) void k_scores(const float* __restrict__ enc,
    const int* __restrict__ slen, const float* __restrict__ a2w,
    const float* __restrict__ a2b, float* __restrict__ ws){
  int t = threadIdx.x;
  int lane = t & 63;
  // p (all waves redundantly)
  float pacc = 0.f;
  #pragma unroll
  for (int j=0; j<2; j++){
    int o = lane*4 + 256*j;
    pacc += dot4(*(const float4*)(a2w+o), *(const float4*)(ws+ATT1_+o));
  }
  pacc = wred(pacc);                       // all lanes have sum
  float Sf = (float)slen[0];
  float p  = Sf * sigf(pacc + a2b[0]);
  int wsi = (int)rintf(fmaxf(p - 64.f, 0.f));
  int wei = (int)rintf(fminf(p + 64.f, Sf - 1.f));
  if (blockIdx.x==0 && t==0){
    ws[SC_] = p;
    ((int*)ws)[IW_]   = wsi;
    ((int*)ws)[IW_+1] = wei;
  }
  int k = blockIdx.x*4 + (t>>6);
  if (k >= WINN) return;
  int idx = wsi + k;
  int smax = slen[0]-1;
  int ci = idx > smax ? smax : (idx < 0 ? 0 : idx);
  const float* er = enc + ((size_t)ci<<10);
  float acc = 0.f;
  #pragma unroll
  for (int j=0; j<4; j++){
    int o = lane*4 + 256*j;
    acc += dot4(*(const float4*)(er+o), *(const float4*)(ws+X_+o));
  }
  acc = wred(acc);
  if (lane==0) ws[A_ + k] = (idx <= wei) ? acc : NEGV;
}

// softmax over 129 + ctx (1024 outputs) in one block
__global__ __launch_bounds__(1024) void k_smctx(const float* __restrict__ enc,
    const int* __restrict__ slen, float* __restrict__ ws, float* __restrict__ aout){
  __shared__ float sarr[WINN];
  __shared__ float av[WINN];
  __shared__ int   ci[WINN];
  __shared__ float red[2];
  int t = threadIdx.x;
  float p = ws[SC_];
  int wsi = ((int*)ws)[IW_], wei = ((int*)ws)[IW_+1];
  int smax = slen[0]-1;
  if (t < WINN){
    sarr[t] = ws[A_ + t];
    int idx = wsi + t;
    ci[t] = idx > smax ? smax : (idx < 0 ? 0 : idx);
  }
  __syncthreads();
  if (t < 64){
    float m = fmaxf(sarr[t], sarr[t+64]);
    if (t==0) m = fmaxf(m, sarr[128]);
    m = wmax(m);
    if (t==0) red[0] = m;
  }
  __syncthreads();
  float M = red[0];
  if (t < 64){
    float e = expf(sarr[t]-M) + expf(sarr[t+64]-M);
    if (t==0) e += expf(sarr[128]-M);
    e = wred(e);
    if (t==0) red[1] = e;
  }
  __syncthreads();
  float sm = red[1];
  if (t < WINN){
    int idx = wsi + t;
    float a = expf(sarr[t]-M) / sm;
    a = (idx <= wei) ? a * expf(((float)idx - p) * (1.f/2048.f)) : 0.f;
    av[t] = a;
    aout[t] = a;
  }
  __syncthreads();
  // ctx: thread t computes element t
  float acc = 0.f;
  for (int k=0; k<WINN; k++) acc += av[k] * enc[((size_t)ci[k]<<10) + t];
  ws[CAT_ + t] = acc;
}

__global__ __launch_bounds__(256) void k_fc1(const float* __restrict__ w,
    const float* __restrict__ b, float* __restrict__ ws, float* __restrict__ oout){
  int gid = blockIdx.x*256 + threadIdx.x;
  int r = gid >> 6, lane = gid & 63;      // r in 0..1023
  const float* wr = w + ((size_t)r<<11);
  float acc = 0.f;
  #pragma unroll
  for (int j=0; j<8; j++){
    int o = lane*4 + 256*j;
    acc += dot4(*(const float4*)(wr+o), *(const float4*)(ws+CAT_+o));
  }
  acc = wred(acc);
  if (lane==0){
    float o = tanhf(acc + b[r]);
    ws[X_ + r] = o;
    oout[r] = o;
  }
}

__global__ __launch_bounds__(512) void k_fc2(const float* __restrict__ w,
    const float* __restrict__ b, float* __restrict__ ws){
  int gid = blockIdx.x*512 + threadIdx.x;
  int r = gid >> 6, lane = gid & 63;      // r in 0..31999
  const float* wr = w + ((size_t)r<<10);
  float acc = 0.f;
  #pragma unroll
  for (int j=0; j<4; j++){
    int o = lane*4 + 256*j;
    acc += dot4(*(const float4*)(wr+o), *(const float4*)(ws+X_+o));
  }
  acc = wred(acc);
  if (lane==0) ws[LOG_ + r] = acc + b[r];
}

// 32 blocks: per-block max + sumexp partials (single read pass)
__global__ __launch_bounds__(256) void k_lsepart(float* __restrict__ ws){
  __shared__ float red[4];
  int b = blockIdx.x, t = threadIdx.x;
  int base = b*1024;
  int n = (b==31) ? 256 : 1024;           // 31*1024 + 256 = 32000
  bool act = (t*4 < n);
  float4 v = make_float4(0.f,0.f,0.f,0.f);
  if (act) v = *(const float4*)(ws + LOG_ + base + t*4);
  float m = act ? fmaxf(fmaxf(v.x,v.y), fmaxf(v.z,v.w)) : -INFINITY;
  m = wmax(m);
  if ((t&63)==0) red[t>>6] = m;
  __syncthreads();
  float M = fmaxf(fmaxf(red[0],red[1]), fmaxf(red[2],red[3]));
  __syncthreads();
  float s = act ? (expf(v.x-M)+expf(v.y-M)+expf(v.z-M)+expf(v.w-M)) : 0.f;
  s = wred(s);
  if ((t&63)==0) red[t>>6] = s;
  __syncthreads();
  if (t==0){
    ws[PART_ + b]      = M;
    ws[PART_ + 32 + b] = red[0]+red[1]+red[2]+red[3];
  }
}

__global__ __launch_bounds__(256) void k_y(const float* __restrict__ ws, float* __restrict__ y){
  int i = blockIdx.x*256 + threadIdx.x;   // float4 index, need 8000
  float M = -INFINITY;
  #pragma unroll
  for (int k=0; k<32; k++) M = fmaxf(M, ws[PART_+k]);
  float S = 0.f;
  #pragma unroll
  for (int k=0; k<32; k++) S += ws[PART_+32+k] * expf(ws[PART_+k] - M);
  float off = M + logf(S);
  if (i < 8000){
    float4 v = *(const float4*)(ws + LOG_ + i*4);
    v.x -= off; v.y -= off; v.z -= off; v.w -= off;
    *(float4*)(y + i*4) = v;
  }
}

extern "C" void kernel_launch(void* const* d_in, const int* in_sizes, int n_in,
                              void* d_out, int out_size, void* d_ws, size_t ws_size,
                              hipStream_t stream) {
  const int*   slen = (const int*)d_in[0];
  const float* enc  = (const float*)d_in[1];
  const int*   word = (const int*)d_in[2];
  const float* h0   = (const float*)d_in[3];
  const float* c0   = (const float*)d_in[4];
  const float* emb  = (const float*)d_in[5];
  const float* wih  = (const float*)d_in[6];
  const float* whh  = (const float*)d_in[7];
  const float* bih  = (const float*)d_in[8];
  const float* bhh  = (const float*)d_in[9];
  const float* a1w  = (const float*)d_in[10];
  const float* a1b  = (const float*)d_in[11];
  const float* a2w  = (const float*)d_in[12];
  const float* a2b  = (const float*)d_in[13];
  const float* f1w  = (const float*)d_in[14];
  const float* f1b  = (const float*)d_in[15];
  const float* f2w  = (const float*)d_in[16];
  const float* f2b  = (const float*)d_in[17];
  float* ws  = (float*)d_ws;
  float* out = (float*)d_out;

  // layer 0: x = embedding row (read in-kernel), h = h0[0]
  k_lstm_gemv<<<1024,256,0,stream>>>(wih, whh, bih, bhh,
                                     nullptr, word, emb, h0, ws + G_);
  k_lstm_act<<<4,256,0,stream>>>(ws + G_, c0, ws, out + O_HN, out + O_CN, 0);
  // layer 1: x = h from layer 0, h = h0[1]
  k_lstm_gemv<<<1024,256,0,stream>>>(wih + (size_t)H4*HDIM, whh + (size_t)H4*HDIM,
                                     bih + H4, bhh + H4,
                                     ws + X_, nullptr, nullptr, h0 + HDIM, ws + G_);
  k_lstm_act<<<4,256,0,stream>>>(ws + G_, c0 + HDIM, ws, out + O_HN + HDIM, out + O_CN + HDIM, 1);

  k_att1<<<128,256,0,stream>>>(a1w, a1b, ws);
  k_scores<<<33,256,0,stream>>>(enc, slen, a2w, a2b, ws);
  k_smctx<<<1,1024,0,stream>>>(enc, slen, ws, out + O_A);
  k_fc1<<<256,256,0,stream>>>(f1w, f1b, ws, out + O_OUT);
  k_fc2<<<4000,512,0,stream>>>(f2w, f2b, ws);
  k_lsepart<<<32,256,0,stream>>>(ws);
  k_y<<<32,256,0,stream>>>(ws, out + O_Y);
}